// Round 11
// baseline (307.375 us; speedup 1.0000x reference)
//
#include <hip/hip_runtime.h>
#include <cmath>

// CXLoss MFMA pipeline, revision 10 (resubmit): barrier-free K-loop.
// A-fragments load directly global->VGPR (no LDS staging, no __syncthreads
// in the K-loop -> no forced vmcnt(0) drains). B register-resident as before.

#define NB 4
#define CC 256
#define HW 4096
#define NQ 4   // loop-dim split per sweep (partials combined later)

static constexpr float kEPS = 1e-8f;
static constexpr float kSIG = 0.1f + 1e-8f;

typedef __attribute__((ext_vector_type(8)))  short short8;
typedef __attribute__((ext_vector_type(16))) float f32x16;

// workspace layout (float units)
enum {
  OFF_MEAN = 0,                      // 256 channel means
  OFF_INVT = 256,                    // NB*HW inv-norms (target)
  OFF_INVI = OFF_INVT + NB*HW,       // NB*HW inv-norms (input)
  OFF_BETA = OFF_INVI + NB*HW,       // NB*HW beta
  OFF_AG   = OFF_BETA + NB*HW,       // NB*HW alpha -> gamma
  OFF_CMAX = OFF_AG   + NB*HW,       // NQ*NB*HW colmax partials
  OFF_WSUM = OFF_CMAX + NQ*NB*HW,    // NQ*NB*HW Wsum partials
  OFF_MAXV = OFF_WSUM + NQ*NB*HW,    // NQ*NB*HW maxv partials
  OFF_END_SMALL = OFF_MAXV + NQ*NB*HW,
  OFF_GT = OFF_END_SMALL,            // NB*HW*CC bf16 (ushort) normalized T
  OFF_GI = OFF_GT + NB*HW*CC/2,      // NB*HW*CC bf16 (ushort) normalized I
  WS_FLOATS_FULL = OFF_GI + NB*HW*CC/2
};

__device__ __forceinline__ ushort cvt_bf16(float x) {
  unsigned u = __float_as_uint(x);
  unsigned r = (u + 0x7fffu + ((u >> 16) & 1u)) >> 16;  // round-nearest-even
  return (ushort)r;
}

__device__ __forceinline__ float blockSum256(float v) {
  __shared__ float sh[4];
  const int lane = threadIdx.x & 63, wv = threadIdx.x >> 6;
  #pragma unroll
  for (int o = 32; o > 0; o >>= 1) v += __shfl_down(v, o, 64);
  __syncthreads();
  if (lane == 0) sh[wv] = v;
  __syncthreads();
  return sh[0] + sh[1] + sh[2] + sh[3];
}

// K1: per-channel mean of featureT over (n,h,w). grid=256
__global__ __launch_bounds__(256) void k_mean3(const float* __restrict__ fT,
                                               float* __restrict__ ws) {
  const int c = blockIdx.x, t = threadIdx.x;
  float s = 0.f;
  for (int n = 0; n < NB; ++n) {
    const float* p = fT + (size_t)(n*CC + c)*HW;
    #pragma unroll
    for (int k = 0; k < 16; ++k) s += p[k*256 + t];
  }
  const float tot = blockSum256(s);
  if (t == 0) ws[OFF_MEAN + c] = tot * (1.0f/16384.0f);
}

// K2: per-pixel inverse channel-norms for both tensors. grid=256
__global__ __launch_bounds__(256) void k_norms3(const float* __restrict__ fT,
                                                const float* __restrict__ fI,
                                                float* __restrict__ ws) {
  __shared__ float sT[4][64], sI[4][64];
  const int t = threadIdx.x, q = t & 63, a = t >> 6;
  const int n = blockIdx.x >> 6;
  const int q0 = (blockIdx.x & 63) * 64;
  const float* mean = ws + OFF_MEAN;
  float accT = 0.f, accI = 0.f;
  for (int i = 0; i < 64; ++i) {
    const int c = a*64 + i;
    const float m = mean[c];
    const size_t base = (size_t)(n*CC + c)*HW + q0 + q;
    const float vT = fT[base] - m; accT += vT*vT;
    const float vI = fI[base] - m; accI += vI*vI;
  }
  sT[a][q] = accT; sI[a][q] = accI;
  __syncthreads();
  if (t < 64) {
    const float ssT = sT[0][t] + sT[1][t] + sT[2][t] + sT[3][t];
    const float ssI = sI[0][t] + sI[1][t] + sI[2][t] + sI[3][t];
    ws[OFF_INVT + n*HW + q0 + t] = 1.0f/(sqrtf(ssT) + kEPS);
    ws[OFF_INVI + n*HW + q0 + t] = 1.0f/(sqrtf(ssI) + kEPS);
  }
}

// K3: normalize + transpose both tensors to bf16 [n][p][c]. grid=2048
__global__ __launch_bounds__(256) void k_prep3(const float* __restrict__ fT,
                                               const float* __restrict__ fI,
                                               float* __restrict__ ws) {
  __shared__ float stage[64][65];    // [p][c]
  const int t = threadIdx.x;
  int bid = blockIdx.x;
  const int tensor = (bid >= 1024); bid &= 1023;
  const int n  = bid >> 8;
  const int pt = (bid & 255) >> 2;
  const int ct = bid & 3;
  const int p0 = pt * 64, c0 = ct * 64;

  const float* __restrict__ src = tensor ? fI : fT;
  const float* __restrict__ inv = ws + (tensor ? OFF_INVI : OFF_INVT);
  ushort* __restrict__ dst = (ushort*)(ws + (tensor ? OFF_GI : OFF_GT));

  const int pcol = t & 63, crb = t >> 6;
  const float invv = inv[n*HW + p0 + pcol];
  #pragma unroll
  for (int i = 0; i < 16; ++i) {
    const int cr = crb + 4*i;
    const float m = ws[OFF_MEAN + c0 + cr];
    const float v = src[((size_t)(n*CC + c0 + cr))*HW + p0 + pcol];
    stage[pcol][cr] = (v - m) * invv;
  }
  __syncthreads();
  const int cpi = t & 31, prb = t >> 5;
  #pragma unroll
  for (int j = 0; j < 8; ++j) {
    const int p = prb + 8*j;
    ushort2 u;
    u.x = cvt_bf16(stage[p][2*cpi]);
    u.y = cvt_bf16(stage[p][2*cpi + 1]);
    *(ushort2*)(dst + ((size_t)(n*HW + p0 + p))*CC + c0 + 2*cpi) = u;
  }
}

// ---------------- MFMA sweep, barrier-free K-loop -------------------------
// s[m][n] = sum_c gL[m][c]*gR[n][c]  (m = loop dim, n = resident dim)
// mode 0: colmax_q = max_m s ; mode 1: Wsum_q = sum_m exp(a_q + b_q s)
// mode 2: maxv_p = max_m (g_m + b_m s)
// A fragment (verified via R5's LDS path): lane holds A[m = ln31 + base]
// [k = kcl*16 + lhi*8 + j] -> 16B contiguous global load per lane.
// grid = NB*32strips*NQ = 512 blocks, 256 threads, 2 blocks/CU.
__global__ __launch_bounds__(256, 2) void k_sweep_mfma3(
    const ushort* __restrict__ gL, const ushort* __restrict__ gR,
    float* __restrict__ ws, const int mode)
{
  __shared__ ushort Bt[128][72];   // B preload staging only (K-loop unused)
  __shared__ float red[2][128];
  __shared__ float gall[1024], ball[1024];  // mode-2 row params, all 8 tiles

  const int t = threadIdx.x;
  const int w = t >> 6, l = t & 63;
  const int wm = w >> 1, wn = w & 1;
  const int ln31 = l & 31, lhi = l >> 5;

  const int b = blockIdx.x;
  const int h = b & 3, sid = b >> 2;
  const int n = sid >> 5;
  const int col0 = (sid & 31) * 128;
  const int loop0 = h * 1024;

  const size_t baseNC = (size_t)n * HW * CC;
  const ushort* __restrict__ gLn = gL + baseNC;

  // staging coords for B preload: chunk q_i = i*256 + t
  const int srow[4] = { (0*256+t)>>3, (1*256+t)>>3, (2*256+t)>>3, (3*256+t)>>3 };
  const int skg8[4] = { ((0*256+t)&7)*8, ((1*256+t)&7)*8, ((2*256+t)&7)*8, ((3*256+t)&7)*8 };

  // ---- preload resident (B) fragments: 16 kc x 2 in ----
  short8 breg[16][2];
  #pragma unroll
  for (int c2 = 0; c2 < 4; ++c2) {
    __syncthreads();
    #pragma unroll
    for (int i = 0; i < 4; ++i) {
      *(short8*)&Bt[srow[i]][skg8[i]] =
        *(const short8*)(gR + baseNC + (size_t)(col0 + srow[i])*CC + c2*64 + skg8[i]);
    }
    __syncthreads();
    #pragma unroll
    for (int kcl = 0; kcl < 4; ++kcl)
      #pragma unroll
      for (int in = 0; in < 2; ++in)
        breg[c2*4 + kcl][in] =
          *(const short8*)&Bt[wn*64 + in*32 + ln31][kcl*16 + lhi*8];
  }

  // ---- stage mode-2 row params for the whole 1024-row strip, once ----
  if (mode == 2) {
    #pragma unroll
    for (int i = 0; i < 4; ++i) {
      gall[i*256 + t] = ws[OFF_AG   + n*HW + loop0 + i*256 + t];
      ball[i*256 + t] = ws[OFF_BETA + n*HW + loop0 + i*256 + t];
    }
  }
  __syncthreads();

  float aq[2], bq[2];   // mode-1 params per resident column
  if (mode == 1) {
    #pragma unroll
    for (int in = 0; in < 2; ++in) {
      const int q = col0 + wn*64 + in*32 + ln31;
      aq[in] = ws[OFF_AG   + n*HW + q];
      bq[in] = ws[OFF_BETA + n*HW + q];
    }
  }

  float runl[2];
  runl[0] = runl[1] = (mode == 1) ? 0.0f : -3.0e38f;

  for (int tile = 0; tile < 8; ++tile) {
    const int rowb = loop0 + tile*128 + wm*64 + ln31;  // im adds 32
    f32x16 acc[2][2];
    #pragma unroll
    for (int im = 0; im < 2; ++im)
      #pragma unroll
      for (int in = 0; in < 2; ++in)
        #pragma unroll
        for (int e = 0; e < 16; ++e) acc[im][in][e] = 0.f;

    // 32 independent 16B loads + 64 MFMAs, fully unrolled, NO barriers:
    // compiler interleaves with partial vmcnt waits.
    #pragma unroll
    for (int c2 = 0; c2 < 4; ++c2) {
      #pragma unroll
      for (int kcl = 0; kcl < 4; ++kcl) {
        const int colb = c2*64 + kcl*16 + lhi*8;
        const short8 a0 = *(const short8*)(gLn + (size_t)(rowb +  0)*CC + colb);
        const short8 a1 = *(const short8*)(gLn + (size_t)(rowb + 32)*CC + colb);
        const int kc = c2*4 + kcl;
        acc[0][0] = __builtin_amdgcn_mfma_f32_32x32x16_bf16(a0, breg[kc][0], acc[0][0], 0, 0, 0);
        acc[0][1] = __builtin_amdgcn_mfma_f32_32x32x16_bf16(a0, breg[kc][1], acc[0][1], 0, 0, 0);
        acc[1][0] = __builtin_amdgcn_mfma_f32_32x32x16_bf16(a1, breg[kc][0], acc[1][0], 0, 0, 0);
        acc[1][1] = __builtin_amdgcn_mfma_f32_32x32x16_bf16(a1, breg[kc][1], acc[1][1], 0, 0, 0);
      }
    }

    // per-lane transform + accumulate (no cross-lane work here).
    // C/D map: col = lane&31, row = (reg&3) + 8*(reg>>2) + 4*(lane>>5)
    if (mode == 0) {
      #pragma unroll
      for (int in = 0; in < 2; ++in) {
        float m = runl[in];
        #pragma unroll
        for (int im = 0; im < 2; ++im)
          #pragma unroll
          for (int r = 0; r < 16; ++r) m = fmaxf(m, acc[im][in][r]);
        runl[in] = m;
      }
    } else if (mode == 1) {
      #pragma unroll
      for (int in = 0; in < 2; ++in) {
        float s = 0.f;
        #pragma unroll
        for (int im = 0; im < 2; ++im)
          #pragma unroll
          for (int r = 0; r < 16; ++r)
            s += __expf(fmaf(bq[in], acc[im][in][r], aq[in]));
        runl[in] += s;
      }
    } else {
      const int tb = tile*128 + wm*64 + 4*lhi;
      #pragma unroll
      for (int in = 0; in < 2; ++in) {
        float m = runl[in];
        #pragma unroll
        for (int im = 0; im < 2; ++im) {
          #pragma unroll
          for (int rg = 0; rg < 4; ++rg) {
            const int rb = tb + im*32 + 8*rg;
            const float4 g4 = *(const float4*)&gall[rb];
            const float4 b4 = *(const float4*)&ball[rb];
            m = fmaxf(m, fmaf(b4.x, acc[im][in][rg*4+0], g4.x));
            m = fmaxf(m, fmaf(b4.y, acc[im][in][rg*4+1], g4.y));
            m = fmaxf(m, fmaf(b4.z, acc[im][in][rg*4+2], g4.z));
            m = fmaxf(m, fmaf(b4.w, acc[im][in][rg*4+3], g4.w));
          }
        }
        runl[in] = m;
      }
    }
  }

  // ---- single cross-lane + cross-wave reduction at the end ----
  #pragma unroll
  for (int in = 0; in < 2; ++in) {
    const float o = __shfl_xor(runl[in], 32, 64);
    runl[in] = (mode == 1) ? (runl[in] + o) : fmaxf(runl[in], o);
  }
  if (l < 32) {
    red[wm][wn*64 +  0 + ln31] = runl[0];
    red[wm][wn*64 + 32 + ln31] = runl[1];
  }
  __syncthreads();
  if (t < 128) {
    const float rv = (mode == 1) ? (red[0][t] + red[1][t])
                                 : fmaxf(red[0][t], red[1][t]);
    const int base = (mode == 0) ? OFF_CMAX : ((mode == 1) ? OFF_WSUM : OFF_MAXV);
    ws[base + h*(NB*HW) + n*HW + col0 + t] = rv;
  }
}

// K4: combine colmax partials -> alpha,beta per (n,q). grid=64
__global__ __launch_bounds__(256) void k_params3(float* __restrict__ ws) {
  const int idx = blockIdx.x*256 + threadIdx.x;
  float cm = ws[OFF_CMAX + idx];
  #pragma unroll
  for (int h = 1; h < NQ; ++h) cm = fmaxf(cm, ws[OFF_CMAX + h*(NB*HW) + idx]);
  const float div   = 0.5f*(1.0f - cm);
  const float inv2d = 1.0f/(2.0f*(div + kEPS));
  ws[OFF_BETA + idx] = inv2d / kSIG;
  ws[OFF_AG   + idx] = (1.0f - inv2d) / kSIG;
}

// K5: gamma = alpha - log(Wsum + eps). grid=64
__global__ __launch_bounds__(256) void k_gamma3(float* __restrict__ ws) {
  const int idx = blockIdx.x*256 + threadIdx.x;
  float s = 0.f;
  #pragma unroll
  for (int h = 0; h < NQ; ++h) s += ws[OFF_WSUM + h*(NB*HW) + idx];
  ws[OFF_AG + idx] = ws[OFF_AG + idx] - logf(s + kEPS);
}

// K6: final loss reduction. one block.
__global__ __launch_bounds__(256) void k_final3(const float* __restrict__ ws,
                                                float* __restrict__ out) {
  const int t = threadIdx.x;
  float loss = 0.f;
  for (int n = 0; n < NB; ++n) {
    float s = 0.f;
    for (int k = 0; k < 16; ++k) {
      const int idx = n*HW + k*256 + t;
      float mv = ws[OFF_MAXV + idx];
      #pragma unroll
      for (int h = 1; h < NQ; ++h) mv = fmaxf(mv, ws[OFF_MAXV + h*(NB*HW) + idx]);
      s += __expf(mv);
    }
    const float tot = blockSum256(s);
    loss += -logf(tot*(1.0f/4096.0f) + kEPS);
  }
  if (t == 0) out[0] = loss*0.25f;
}

extern "C" void kernel_launch(void* const* d_in, const int* in_sizes, int n_in,
                              void* d_out, int out_size, void* d_ws, size_t ws_size,
                              hipStream_t stream) {
  const float* fT = (const float*)d_in[0];
  const float* fI = (const float*)d_in[1];
  float* out = (float*)d_out;
  float* ws  = (float*)d_ws;

  const size_t need_full = (size_t)WS_FLOATS_FULL * sizeof(float);
  if (ws_size < need_full) return;  // ws measured 256 MB (R2); guard only

  const ushort* GT = (const ushort*)(ws + OFF_GT);
  const ushort* GI = (const ushort*)(ws + OFF_GI);
  k_mean3      <<<256,  256, 0, stream>>>(fT, ws);
  k_norms3     <<<256,  256, 0, stream>>>(fT, fI, ws);
  k_prep3      <<<2048, 256, 0, stream>>>(fT, fI, ws);
  k_sweep_mfma3<<<512,  256, 0, stream>>>(GT, GI, ws, 0);  // colmax
  k_params3    <<<64,   256, 0, stream>>>(ws);
  k_sweep_mfma3<<<512,  256, 0, stream>>>(GT, GI, ws, 1);  // Wsum
  k_gamma3     <<<64,   256, 0, stream>>>(ws);
  k_sweep_mfma3<<<512,  256, 0, stream>>>(GI, GT, ws, 2);  // maxv
  k_final3     <<<1,    256, 0, stream>>>(ws, out);
}

// Round 13
// 244.800 us; speedup vs baseline: 1.2556x; 1.2556x over previous
//
#include <hip/hip_runtime.h>
#include <cmath>

// CXLoss MFMA pipeline, revision 12 (resubmit; prior round was an infra
// failure): double-buffered LDS K-loop, ONE barrier per chunk, prefetch
// issued AFTER the barrier (so the forced vmcnt(0) at the next barrier finds
// the loads already landed). Coalesced staging restored (R11's direct
// per-lane A-loads lost coalescing: 32 x 512B-strided lines).
// B-fragments: one-time direct global->VGPR preload (no barriers).

#define NB 4
#define CC 256
#define HW 4096
#define NQ 4   // loop-dim split per sweep (partials combined later)

static constexpr float kEPS = 1e-8f;
static constexpr float kSIG = 0.1f + 1e-8f;

typedef __attribute__((ext_vector_type(8)))  short short8;
typedef __attribute__((ext_vector_type(16))) float f32x16;

// workspace layout (float units)
enum {
  OFF_MEAN = 0,                      // 256 channel means
  OFF_INVT = 256,                    // NB*HW inv-norms (target)
  OFF_INVI = OFF_INVT + NB*HW,       // NB*HW inv-norms (input)
  OFF_BETA = OFF_INVI + NB*HW,       // NB*HW beta
  OFF_AG   = OFF_BETA + NB*HW,       // NB*HW alpha -> gamma
  OFF_CMAX = OFF_AG   + NB*HW,       // NQ*NB*HW colmax partials
  OFF_WSUM = OFF_CMAX + NQ*NB*HW,    // NQ*NB*HW Wsum partials
  OFF_MAXV = OFF_WSUM + NQ*NB*HW,    // NQ*NB*HW maxv partials
  OFF_END_SMALL = OFF_MAXV + NQ*NB*HW,
  OFF_GT = OFF_END_SMALL,            // NB*HW*CC bf16 (ushort) normalized T
  OFF_GI = OFF_GT + NB*HW*CC/2,      // NB*HW*CC bf16 (ushort) normalized I
  WS_FLOATS_FULL = OFF_GI + NB*HW*CC/2
};

__device__ __forceinline__ ushort cvt_bf16(float x) {
  unsigned u = __float_as_uint(x);
  unsigned r = (u + 0x7fffu + ((u >> 16) & 1u)) >> 16;  // round-nearest-even
  return (ushort)r;
}

__device__ __forceinline__ float blockSum256(float v) {
  __shared__ float sh[4];
  const int lane = threadIdx.x & 63, wv = threadIdx.x >> 6;
  #pragma unroll
  for (int o = 32; o > 0; o >>= 1) v += __shfl_down(v, o, 64);
  __syncthreads();
  if (lane == 0) sh[wv] = v;
  __syncthreads();
  return sh[0] + sh[1] + sh[2] + sh[3];
}

// K1: per-channel mean of featureT over (n,h,w). grid=256
__global__ __launch_bounds__(256) void k_mean4(const float* __restrict__ fT,
                                               float* __restrict__ ws) {
  const int c = blockIdx.x, t = threadIdx.x;
  float s = 0.f;
  for (int n = 0; n < NB; ++n) {
    const float* p = fT + (size_t)(n*CC + c)*HW;
    #pragma unroll
    for (int k = 0; k < 16; ++k) s += p[k*256 + t];
  }
  const float tot = blockSum256(s);
  if (t == 0) ws[OFF_MEAN + c] = tot * (1.0f/16384.0f);
}

// K2: per-pixel inverse channel-norms for both tensors. grid=256
__global__ __launch_bounds__(256) void k_norms4(const float* __restrict__ fT,
                                                const float* __restrict__ fI,
                                                float* __restrict__ ws) {
  __shared__ float sT[4][64], sI[4][64];
  const int t = threadIdx.x, q = t & 63, a = t >> 6;
  const int n = blockIdx.x >> 6;
  const int q0 = (blockIdx.x & 63) * 64;
  const float* mean = ws + OFF_MEAN;
  float accT = 0.f, accI = 0.f;
  for (int i = 0; i < 64; ++i) {
    const int c = a*64 + i;
    const float m = mean[c];
    const size_t base = (size_t)(n*CC + c)*HW + q0 + q;
    const float vT = fT[base] - m; accT += vT*vT;
    const float vI = fI[base] - m; accI += vI*vI;
  }
  sT[a][q] = accT; sI[a][q] = accI;
  __syncthreads();
  if (t < 64) {
    const float ssT = sT[0][t] + sT[1][t] + sT[2][t] + sT[3][t];
    const float ssI = sI[0][t] + sI[1][t] + sI[2][t] + sI[3][t];
    ws[OFF_INVT + n*HW + q0 + t] = 1.0f/(sqrtf(ssT) + kEPS);
    ws[OFF_INVI + n*HW + q0 + t] = 1.0f/(sqrtf(ssI) + kEPS);
  }
}

// K3: normalize + transpose both tensors to bf16 [n][p][c]. grid=2048
__global__ __launch_bounds__(256) void k_prep4(const float* __restrict__ fT,
                                               const float* __restrict__ fI,
                                               float* __restrict__ ws) {
  __shared__ float stage[64][65];    // [p][c]
  const int t = threadIdx.x;
  int bid = blockIdx.x;
  const int tensor = (bid >= 1024); bid &= 1023;
  const int n  = bid >> 8;
  const int pt = (bid & 255) >> 2;
  const int ct = bid & 3;
  const int p0 = pt * 64, c0 = ct * 64;

  const float* __restrict__ src = tensor ? fI : fT;
  const float* __restrict__ inv = ws + (tensor ? OFF_INVI : OFF_INVT);
  ushort* __restrict__ dst = (ushort*)(ws + (tensor ? OFF_GI : OFF_GT));

  const int pcol = t & 63, crb = t >> 6;
  const float invv = inv[n*HW + p0 + pcol];
  #pragma unroll
  for (int i = 0; i < 16; ++i) {
    const int cr = crb + 4*i;
    const float m = ws[OFF_MEAN + c0 + cr];
    const float v = src[((size_t)(n*CC + c0 + cr))*HW + p0 + pcol];
    stage[pcol][cr] = (v - m) * invv;
  }
  __syncthreads();
  const int cpi = t & 31, prb = t >> 5;
  #pragma unroll
  for (int j = 0; j < 8; ++j) {
    const int p = prb + 8*j;
    ushort2 u;
    u.x = cvt_bf16(stage[p][2*cpi]);
    u.y = cvt_bf16(stage[p][2*cpi + 1]);
    *(ushort2*)(dst + ((size_t)(n*HW + p0 + p))*CC + c0 + 2*cpi) = u;
  }
}

// ---------------- MFMA sweep, double-buffered 1-barrier K-loop ------------
// s[m][n] = sum_c gL[m][c]*gR[n][c]  (m = loop dim, n = resident dim)
// mode 0: colmax_q = max_m s ; mode 1: Wsum_q = sum_m exp(a_q + b_q s)
// mode 2: maxv_p = max_m (g_m + b_m s)
// grid = NB*32strips*NQ = 512 blocks, 256 threads, 2 blocks/CU.
__global__ __launch_bounds__(256, 2) void k_sweep_mfma4(
    const ushort* __restrict__ gL, const ushort* __restrict__ gR,
    float* __restrict__ ws, const int mode)
{
  __shared__ ushort At[2][128][72];   // double-buffered K=64 chunk (+8 pad)
  __shared__ float red[2][128];
  __shared__ float gall[1024], ball[1024];  // mode-2 row params, whole strip

  const int t = threadIdx.x;
  const int w = t >> 6, l = t & 63;
  const int wm = w >> 1, wn = w & 1;
  const int ln31 = l & 31, lhi = l >> 5;

  const int b = blockIdx.x;
  const int h = b & 3, sid = b >> 2;
  const int n = sid >> 5;
  const int col0 = (sid & 31) * 128;
  const int loop0 = h * 1024;

  const size_t baseNC = (size_t)n * HW * CC;
  const ushort* __restrict__ gLn = gL + baseNC;

  // staging coords (coalesced): chunk q_i = i*256 + t -> row, 16B-group
  const int srow[4] = { (0*256+t)>>3, (1*256+t)>>3, (2*256+t)>>3, (3*256+t)>>3 };
  const int skg8[4] = { ((0*256+t)&7)*8, ((1*256+t)&7)*8, ((2*256+t)&7)*8, ((3*256+t)&7)*8 };

  // ---- issue chunk-0 loads first (oldest -> earliest vmcnt retirement) ----
  short8 pf[4];
  #pragma unroll
  for (int i = 0; i < 4; ++i)
    pf[i] = *(const short8*)(gLn + (size_t)(loop0 + srow[i])*CC + 0*64 + skg8[i]);

  // ---- B fragments: one-time direct global->VGPR (no barriers) ----
  // breg[c2*4+kcl][in] = B[col0 + wn*64 + in*32 + ln31][c2*64 + kcl*16 + lhi*8 ..+8]
  short8 breg[16][2];
  #pragma unroll
  for (int c2 = 0; c2 < 4; ++c2)
    #pragma unroll
    for (int kcl = 0; kcl < 4; ++kcl)
      #pragma unroll
      for (int in = 0; in < 2; ++in)
        breg[c2*4 + kcl][in] = *(const short8*)(
          gR + baseNC + (size_t)(col0 + wn*64 + in*32 + ln31)*CC
             + c2*64 + kcl*16 + lhi*8);

  // ---- write chunk 0 into buf0; then issue chunk-1 loads ----
  #pragma unroll
  for (int i = 0; i < 4; ++i)
    *(short8*)&At[0][srow[i]][skg8[i]] = pf[i];
  #pragma unroll
  for (int i = 0; i < 4; ++i)
    pf[i] = *(const short8*)(gLn + (size_t)(loop0 + srow[i])*CC + 1*64 + skg8[i]);

  // mode-2: stage row params for the whole 1024-row strip once
  if (mode == 2) {
    #pragma unroll
    for (int i = 0; i < 4; ++i) {
      gall[i*256 + t] = ws[OFF_AG   + n*HW + loop0 + i*256 + t];
      ball[i*256 + t] = ws[OFF_BETA + n*HW + loop0 + i*256 + t];
    }
  }
  float aq[2], bq[2];   // mode-1 params per resident column
  if (mode == 1) {
    #pragma unroll
    for (int in = 0; in < 2; ++in) {
      const int q = col0 + wn*64 + in*32 + ln31;
      aq[in] = ws[OFF_AG   + n*HW + q];
      bq[in] = ws[OFF_BETA + n*HW + q];
    }
  }

  float runl[2];
  runl[0] = runl[1] = (mode == 1) ? 0.0f : -3.0e38f;

  for (int tile = 0; tile < 8; ++tile) {
    const int tile0 = loop0 + tile*128;
    f32x16 acc[2][2];
    #pragma unroll
    for (int im = 0; im < 2; ++im)
      #pragma unroll
      for (int in = 0; in < 2; ++in)
        #pragma unroll
        for (int e = 0; e < 16; ++e) acc[im][in][e] = 0.f;

    #pragma unroll
    for (int c2 = 0; c2 < 4; ++c2) {
      // chunk k = tile*4 + c2; compute from buf[c2&1], write buf[(c2+1)&1].
      // ONE barrier per chunk. The pf consumed here was issued one full
      // compute phase ago -> the vmcnt(0) the compiler emits before this
      // s_barrier finds it (mostly) landed.
      __syncthreads();
      if (!(tile == 7 && c2 == 3)) {
        #pragma unroll
        for (int i = 0; i < 4; ++i)
          *(short8*)&At[(c2+1)&1][srow[i]][skg8[i]] = pf[i];
        // issue loads for chunk k+2 AFTER the barrier (hidden under compute)
        if (!(tile == 7 && c2 >= 2)) {
          const int ntile0 = loop0 + (tile + (c2 >= 2 ? 1 : 0))*128;
          const int nc2 = (c2 + 2) & 3;
          #pragma unroll
          for (int i = 0; i < 4; ++i)
            pf[i] = *(const short8*)(gLn + (size_t)(ntile0 + srow[i])*CC
                                         + nc2*64 + skg8[i]);
        }
      }
      #pragma unroll
      for (int kcl = 0; kcl < 4; ++kcl) {
        const short8 a0 = *(const short8*)&At[c2&1][wm*64 +  0 + ln31][kcl*16 + lhi*8];
        const short8 a1 = *(const short8*)&At[c2&1][wm*64 + 32 + ln31][kcl*16 + lhi*8];
        const int kc = c2*4 + kcl;   // static (both loops unrolled)
        acc[0][0] = __builtin_amdgcn_mfma_f32_32x32x16_bf16(a0, breg[kc][0], acc[0][0], 0, 0, 0);
        acc[0][1] = __builtin_amdgcn_mfma_f32_32x32x16_bf16(a0, breg[kc][1], acc[0][1], 0, 0, 0);
        acc[1][0] = __builtin_amdgcn_mfma_f32_32x32x16_bf16(a1, breg[kc][0], acc[1][0], 0, 0, 0);
        acc[1][1] = __builtin_amdgcn_mfma_f32_32x32x16_bf16(a1, breg[kc][1], acc[1][1], 0, 0, 0);
      }
    }

    // per-lane transform + accumulate (no cross-lane/cross-wave work here).
    // C/D map: col = lane&31, row = (reg&3) + 8*(reg>>2) + 4*(lane>>5)
    if (mode == 0) {
      #pragma unroll
      for (int in = 0; in < 2; ++in) {
        float m = runl[in];
        #pragma unroll
        for (int im = 0; im < 2; ++im)
          #pragma unroll
          for (int r = 0; r < 16; ++r) m = fmaxf(m, acc[im][in][r]);
        runl[in] = m;
      }
    } else if (mode == 1) {
      #pragma unroll
      for (int in = 0; in < 2; ++in) {
        float s = 0.f;
        #pragma unroll
        for (int im = 0; im < 2; ++im)
          #pragma unroll
          for (int r = 0; r < 16; ++r)
            s += __expf(fmaf(bq[in], acc[im][in][r], aq[in]));
        runl[in] += s;
      }
    } else {
      const int tb = tile*128 + wm*64 + 4*lhi;
      #pragma unroll
      for (int in = 0; in < 2; ++in) {
        float m = runl[in];
        #pragma unroll
        for (int im = 0; im < 2; ++im) {
          #pragma unroll
          for (int rg = 0; rg < 4; ++rg) {
            const int rb = tb + im*32 + 8*rg;
            const float4 g4 = *(const float4*)&gall[rb];
            const float4 b4 = *(const float4*)&ball[rb];
            m = fmaxf(m, fmaf(b4.x, acc[im][in][rg*4+0], g4.x));
            m = fmaxf(m, fmaf(b4.y, acc[im][in][rg*4+1], g4.y));
            m = fmaxf(m, fmaf(b4.z, acc[im][in][rg*4+2], g4.z));
            m = fmaxf(m, fmaf(b4.w, acc[im][in][rg*4+3], g4.w));
          }
        }
        runl[in] = m;
      }
    }
  }

  // ---- single cross-lane + cross-wave reduction at the end ----
  #pragma unroll
  for (int in = 0; in < 2; ++in) {
    const float o = __shfl_xor(runl[in], 32, 64);
    runl[in] = (mode == 1) ? (runl[in] + o) : fmaxf(runl[in], o);
  }
  if (l < 32) {
    red[wm][wn*64 +  0 + ln31] = runl[0];
    red[wm][wn*64 + 32 + ln31] = runl[1];
  }
  __syncthreads();
  if (t < 128) {
    const float rv = (mode == 1) ? (red[0][t] + red[1][t])
                                 : fmaxf(red[0][t], red[1][t]);
    const int base = (mode == 0) ? OFF_CMAX : ((mode == 1) ? OFF_WSUM : OFF_MAXV);
    ws[base + h*(NB*HW) + n*HW + col0 + t] = rv;
  }
}

// K4: combine colmax partials -> alpha,beta per (n,q). grid=64
__global__ __launch_bounds__(256) void k_params4(float* __restrict__ ws) {
  const int idx = blockIdx.x*256 + threadIdx.x;
  float cm = ws[OFF_CMAX + idx];
  #pragma unroll
  for (int h = 1; h < NQ; ++h) cm = fmaxf(cm, ws[OFF_CMAX + h*(NB*HW) + idx]);
  const float div   = 0.5f*(1.0f - cm);
  const float inv2d = 1.0f/(2.0f*(div + kEPS));
  ws[OFF_BETA + idx] = inv2d / kSIG;
  ws[OFF_AG   + idx] = (1.0f - inv2d) / kSIG;
}

// K5: gamma = alpha - log(Wsum + eps). grid=64
__global__ __launch_bounds__(256) void k_gamma4(float* __restrict__ ws) {
  const int idx = blockIdx.x*256 + threadIdx.x;
  float s = 0.f;
  #pragma unroll
  for (int h = 0; h < NQ; ++h) s += ws[OFF_WSUM + h*(NB*HW) + idx];
  ws[OFF_AG + idx] = ws[OFF_AG + idx] - logf(s + kEPS);
}

// K6: final loss reduction. one block.
__global__ __launch_bounds__(256) void k_final4(const float* __restrict__ ws,
                                                float* __restrict__ out) {
  const int t = threadIdx.x;
  float loss = 0.f;
  for (int n = 0; n < NB; ++n) {
    float s = 0.f;
    for (int k = 0; k < 16; ++k) {
      const int idx = n*HW + k*256 + t;
      float mv = ws[OFF_MAXV + idx];
      #pragma unroll
      for (int h = 1; h < NQ; ++h) mv = fmaxf(mv, ws[OFF_MAXV + h*(NB*HW) + idx]);
      s += __expf(mv);
    }
    const float tot = blockSum256(s);
    loss += -logf(tot*(1.0f/4096.0f) + kEPS);
  }
  if (t == 0) out[0] = loss*0.25f;
}

extern "C" void kernel_launch(void* const* d_in, const int* in_sizes, int n_in,
                              void* d_out, int out_size, void* d_ws, size_t ws_size,
                              hipStream_t stream) {
  const float* fT = (const float*)d_in[0];
  const float* fI = (const float*)d_in[1];
  float* out = (float*)d_out;
  float* ws  = (float*)d_ws;

  const size_t need_full = (size_t)WS_FLOATS_FULL * sizeof(float);
  if (ws_size < need_full) return;  // ws measured 256 MB (R2); guard only

  const ushort* GT = (const ushort*)(ws + OFF_GT);
  const ushort* GI = (const ushort*)(ws + OFF_GI);
  k_mean4      <<<256,  256, 0, stream>>>(fT, ws);
  k_norms4     <<<256,  256, 0, stream>>>(fT, fI, ws);
  k_prep4      <<<2048, 256, 0, stream>>>(fT, fI, ws);
  k_sweep_mfma4<<<512,  256, 0, stream>>>(GT, GI, ws, 0);  // colmax
  k_params4    <<<64,   256, 0, stream>>>(ws);
  k_sweep_mfma4<<<512,  256, 0, stream>>>(GT, GI, ws, 1);  // Wsum
  k_gamma4     <<<64,   256, 0, stream>>>(ws);
  k_sweep_mfma4<<<512,  256, 0, stream>>>(GI, GT, ws, 2);  // maxv
  k_final4     <<<1,    256, 0, stream>>>(ws, out);
}

// Round 14
// 241.401 us; speedup vs baseline: 1.2733x; 1.0141x over previous
//
#include <hip/hip_runtime.h>
#include <cmath>

// CXLoss MFMA pipeline, revision 14: fragment-tiled ("swizzled") operand
// layout. k_prep writes normalized bf16 in MFMA-fragment tile order, so the
// sweep loads A and B fragments DIRECTLY global->VGPR, fully coalesced
// (1KB contiguous per wave-load), with zero LDS staging and zero K-loop
// barriers. k_norms is fused into k_prep.
//
// Tile layout: offset_ushort(n, r32, kc) = ((n*128 + r32)*16 + kc)*512 + l*8
//   holds X[n][p = r32*32 + (l&31)][c = kc*16 + (l>>5)*8 + j], j<8.
// (A and B fragments use the identical lane->k map, so any internal HW
// k-permutation cancels — same argument as the verified R5..R13 path.)

#define NB 4
#define CC 256
#define HW 4096
#define NQ 4   // loop-dim split per sweep (partials combined later)

static constexpr float kEPS = 1e-8f;
static constexpr float kSIG = 0.1f + 1e-8f;

typedef __attribute__((ext_vector_type(8)))  short short8;
typedef __attribute__((ext_vector_type(16))) float f32x16;

// workspace layout (float units)
enum {
  OFF_MEAN = 0,                      // 256 channel means
  OFF_BETA = 256,                    // NB*HW beta
  OFF_AG   = OFF_BETA + NB*HW,       // NB*HW alpha -> gamma
  OFF_CMAX = OFF_AG   + NB*HW,       // NQ*NB*HW colmax partials
  OFF_WSUM = OFF_CMAX + NQ*NB*HW,    // NQ*NB*HW Wsum partials
  OFF_MAXV = OFF_WSUM + NQ*NB*HW,    // NQ*NB*HW maxv partials
  OFF_GT   = OFF_MAXV + NQ*NB*HW,    // NB*HW*CC bf16 (ushort), tiled
  OFF_GI   = OFF_GT + NB*HW*CC/2,
  WS_FLOATS_FULL = OFF_GI + NB*HW*CC/2
};

__device__ __forceinline__ ushort cvt_bf16(float x) {
  unsigned u = __float_as_uint(x);
  unsigned r = (u + 0x7fffu + ((u >> 16) & 1u)) >> 16;  // round-nearest-even
  return (ushort)r;
}

__device__ __forceinline__ float blockSum256(float v) {
  __shared__ float sh[4];
  const int lane = threadIdx.x & 63, wv = threadIdx.x >> 6;
  #pragma unroll
  for (int o = 32; o > 0; o >>= 1) v += __shfl_down(v, o, 64);
  __syncthreads();
  if (lane == 0) sh[wv] = v;
  __syncthreads();
  return sh[0] + sh[1] + sh[2] + sh[3];
}

// K1: per-channel mean of featureT over (n,h,w). grid=256
__global__ __launch_bounds__(256) void k_mean5(const float* __restrict__ fT,
                                               float* __restrict__ ws) {
  const int c = blockIdx.x, t = threadIdx.x;
  float s = 0.f;
  for (int n = 0; n < NB; ++n) {
    const float* p = fT + (size_t)(n*CC + c)*HW;
    #pragma unroll
    for (int k = 0; k < 16; ++k) s += p[k*256 + t];
  }
  const float tot = blockSum256(s);
  if (t == 0) ws[OFF_MEAN + c] = tot * (1.0f/16384.0f);
}

// K2: fused normalize (mean-center, channel-L2) + write bf16 in fragment-tile
// order. Block = one tensor x one batch x one 32-pixel tile (r32), all 256 c.
// grid = 2 * NB * 128 = 1024 blocks of 256 threads.
__global__ __launch_bounds__(256) void k_prep5(const float* __restrict__ fT,
                                               const float* __restrict__ fI,
                                               float* __restrict__ ws) {
  __shared__ float stage[32][257];   // [p_local][c], +1 pad
  __shared__ float prt[8][32];
  __shared__ float sinv[32];
  const int t = threadIdx.x, l = t & 63;
  int bid = blockIdx.x;
  const int tensor = (bid >= 512); bid &= 511;
  const int n   = bid >> 7;
  const int r32 = bid & 127;
  const int p0  = r32 * 32;

  const float* __restrict__ src = tensor ? fI : fT;
  ushort* __restrict__ dst = (ushort*)(ws + (tensor ? OFF_GI : OFF_GT));
  const float* __restrict__ mean = ws + OFF_MEAN;

  const int pl = t & 31, cg = t >> 5;          // 8 c-groups x 32 pixels
  float acc = 0.f;
  #pragma unroll
  for (int i = 0; i < 32; ++i) {
    const int c = cg*32 + i;
    const float v = src[((size_t)(n*CC + c))*HW + p0 + pl] - mean[c];
    stage[pl][c] = v;
    acc += v*v;
  }
  prt[cg][pl] = acc;
  __syncthreads();
  if (t < 32) {
    float s = 0.f;
    #pragma unroll
    for (int g = 0; g < 8; ++g) s += prt[g][t];
    sinv[t] = 1.0f/(sqrtf(s) + kEPS);
  }
  __syncthreads();

  // swizzled write: wave w handles kc in [w*4, w*4+4); 1KB tile per wave-store
  const int w = t >> 6, lhi = l >> 5, m = l & 31;
  const float iv = sinv[m];
  #pragma unroll
  for (int i = 0; i < 4; ++i) {
    const int kc = w*4 + i;
    const int cb = kc*16 + lhi*8;
    short8 o;
    #pragma unroll
    for (int j = 0; j < 8; ++j)
      ((ushort*)&o)[j] = cvt_bf16(stage[m][cb + j] * iv);
    *(short8*)(dst + (((size_t)(n*128 + r32)*16 + kc) << 9) + l*8) = o;
  }
}

// ---------------- MFMA sweep: direct-fragment loads, no K-loop barriers ---
// s[m][n] = sum_c gA[m][c]*gB[n][c]  (m = loop dim, n = resident dim)
// mode 0: colmax_q = max_m s ; mode 1: Wsum_q = sum_m exp(a_q + b_q s)
// mode 2: maxv_p = max_m (g_m + b_m s)
// grid = NB*32strips*NQ = 512 blocks, 256 threads, 2 blocks/CU.
__global__ __launch_bounds__(256, 2) void k_sweep_mfma5(
    const ushort* __restrict__ gA, const ushort* __restrict__ gB,
    float* __restrict__ ws, const int mode)
{
  __shared__ float red[2][128];
  __shared__ float gall[1024], ball[1024];  // mode-2 row params, whole strip

  const int t = threadIdx.x;
  const int w = t >> 6, l = t & 63;
  const int wm = w >> 1, wn = w & 1;
  const int ln31 = l & 31, lhi = l >> 5;

  const int b = blockIdx.x;
  const int h = b & 3, sid = b >> 2;
  const int n = sid >> 5;
  const int col0 = (sid & 31) * 128;
  const int loop0 = h * 1024;

  // ---- B fragments: 32 coalesced 16B/lane loads, register-resident ----
  const int RB = (col0 >> 5) + wn*2;
  short8 breg[16][2];
  #pragma unroll
  for (int kc = 0; kc < 16; ++kc)
    #pragma unroll
    for (int in = 0; in < 2; ++in)
      breg[kc][in] = *(const short8*)(gB +
          (((size_t)(n*128 + RB + in)*16 + kc) << 9) + l*8);

  if (mode == 2) {
    #pragma unroll
    for (int i = 0; i < 4; ++i) {
      gall[i*256 + t] = ws[OFF_AG   + n*HW + loop0 + i*256 + t];
      ball[i*256 + t] = ws[OFF_BETA + n*HW + loop0 + i*256 + t];
    }
  }
  float aq[2], bq[2];   // mode-1 params per resident column
  if (mode == 1) {
    #pragma unroll
    for (int in = 0; in < 2; ++in) {
      const int q = col0 + wn*64 + in*32 + ln31;
      aq[in] = ws[OFF_AG   + n*HW + q];
      bq[in] = ws[OFF_BETA + n*HW + q];
    }
  }
  __syncthreads();   // gall/ball visible (only barrier before the end)

  float runl[2];
  runl[0] = runl[1] = (mode == 1) ? 0.0f : -3.0e38f;

  for (int tile = 0; tile < 8; ++tile) {
    // wave wm covers rows RA..RA+1 (r32 units); 32KB contiguous stream/wave
    const int RA = h*32 + tile*4 + wm*2;
    const ushort* __restrict__ pa =
        gA + (((size_t)(n*128 + RA)*16) << 9) + l*8;

    f32x16 acc[2][2];
    #pragma unroll
    for (int im = 0; im < 2; ++im)
      #pragma unroll
      for (int in = 0; in < 2; ++in)
        #pragma unroll
        for (int e = 0; e < 16; ++e) acc[im][in][e] = 0.f;

    // 32 independent coalesced loads + 64 MFMAs, no barriers: compiler
    // interleaves with partial vmcnt waits (AITER-style).
    #pragma unroll
    for (int kc = 0; kc < 16; ++kc) {
      const short8 a0 = *(const short8*)(pa + kc*512);
      const short8 a1 = *(const short8*)(pa + (16 + kc)*512);
      acc[0][0] = __builtin_amdgcn_mfma_f32_32x32x16_bf16(a0, breg[kc][0], acc[0][0], 0, 0, 0);
      acc[0][1] = __builtin_amdgcn_mfma_f32_32x32x16_bf16(a0, breg[kc][1], acc[0][1], 0, 0, 0);
      acc[1][0] = __builtin_amdgcn_mfma_f32_32x32x16_bf16(a1, breg[kc][0], acc[1][0], 0, 0, 0);
      acc[1][1] = __builtin_amdgcn_mfma_f32_32x32x16_bf16(a1, breg[kc][1], acc[1][1], 0, 0, 0);
    }

    // per-lane transform + accumulate.
    // C/D map: col = lane&31, row = (reg&3) + 8*(reg>>2) + 4*(lane>>5)
    if (mode == 0) {
      #pragma unroll
      for (int in = 0; in < 2; ++in) {
        float m = runl[in];
        #pragma unroll
        for (int im = 0; im < 2; ++im)
          #pragma unroll
          for (int r = 0; r < 16; ++r) m = fmaxf(m, acc[im][in][r]);
        runl[in] = m;
      }
    } else if (mode == 1) {
      #pragma unroll
      for (int in = 0; in < 2; ++in) {
        float s = 0.f;
        #pragma unroll
        for (int im = 0; im < 2; ++im)
          #pragma unroll
          for (int r = 0; r < 16; ++r)
            s += __expf(fmaf(bq[in], acc[im][in][r], aq[in]));
        runl[in] += s;
      }
    } else {
      const int tb = tile*128 + wm*64 + 4*lhi;
      #pragma unroll
      for (int in = 0; in < 2; ++in) {
        float m = runl[in];
        #pragma unroll
        for (int im = 0; im < 2; ++im) {
          #pragma unroll
          for (int rg = 0; rg < 4; ++rg) {
            const int rb = tb + im*32 + 8*rg;
            const float4 g4 = *(const float4*)&gall[rb];
            const float4 b4 = *(const float4*)&ball[rb];
            m = fmaxf(m, fmaf(b4.x, acc[im][in][rg*4+0], g4.x));
            m = fmaxf(m, fmaf(b4.y, acc[im][in][rg*4+1], g4.y));
            m = fmaxf(m, fmaf(b4.z, acc[im][in][rg*4+2], g4.z));
            m = fmaxf(m, fmaf(b4.w, acc[im][in][rg*4+3], g4.w));
          }
        }
        runl[in] = m;
      }
    }
  }

  // ---- single cross-lane + cross-wave reduction at the end ----
  #pragma unroll
  for (int in = 0; in < 2; ++in) {
    const float o = __shfl_xor(runl[in], 32, 64);
    runl[in] = (mode == 1) ? (runl[in] + o) : fmaxf(runl[in], o);
  }
  if (l < 32) {
    red[wm][wn*64 +  0 + ln31] = runl[0];
    red[wm][wn*64 + 32 + ln31] = runl[1];
  }
  __syncthreads();
  if (t < 128) {
    const float rv = (mode == 1) ? (red[0][t] + red[1][t])
                                 : fmaxf(red[0][t], red[1][t]);
    const int base = (mode == 0) ? OFF_CMAX : ((mode == 1) ? OFF_WSUM : OFF_MAXV);
    ws[base + h*(NB*HW) + n*HW + col0 + t] = rv;
  }
}

// K4: combine colmax partials -> alpha,beta per (n,q). grid=64
__global__ __launch_bounds__(256) void k_params5(float* __restrict__ ws) {
  const int idx = blockIdx.x*256 + threadIdx.x;
  float cm = ws[OFF_CMAX + idx];
  #pragma unroll
  for (int h = 1; h < NQ; ++h) cm = fmaxf(cm, ws[OFF_CMAX + h*(NB*HW) + idx]);
  const float div   = 0.5f*(1.0f - cm);
  const float inv2d = 1.0f/(2.0f*(div + kEPS));
  ws[OFF_BETA + idx] = inv2d / kSIG;
  ws[OFF_AG   + idx] = (1.0f - inv2d) / kSIG;
}

// K5: gamma = alpha - log(Wsum + eps). grid=64
__global__ __launch_bounds__(256) void k_gamma5(float* __restrict__ ws) {
  const int idx = blockIdx.x*256 + threadIdx.x;
  float s = 0.f;
  #pragma unroll
  for (int h = 0; h < NQ; ++h) s += ws[OFF_WSUM + h*(NB*HW) + idx];
  ws[OFF_AG + idx] = ws[OFF_AG + idx] - logf(s + kEPS);
}

// K6: final loss reduction. one block.
__global__ __launch_bounds__(256) void k_final5(const float* __restrict__ ws,
                                                float* __restrict__ out) {
  const int t = threadIdx.x;
  float loss = 0.f;
  for (int n = 0; n < NB; ++n) {
    float s = 0.f;
    for (int k = 0; k < 16; ++k) {
      const int idx = n*HW + k*256 + t;
      float mv = ws[OFF_MAXV + idx];
      #pragma unroll
      for (int h = 1; h < NQ; ++h) mv = fmaxf(mv, ws[OFF_MAXV + h*(NB*HW) + idx]);
      s += __expf(mv);
    }
    const float tot = blockSum256(s);
    loss += -logf(tot*(1.0f/4096.0f) + kEPS);
  }
  if (t == 0) out[0] = loss*0.25f;
}

extern "C" void kernel_launch(void* const* d_in, const int* in_sizes, int n_in,
                              void* d_out, int out_size, void* d_ws, size_t ws_size,
                              hipStream_t stream) {
  const float* fT = (const float*)d_in[0];
  const float* fI = (const float*)d_in[1];
  float* out = (float*)d_out;
  float* ws  = (float*)d_ws;

  const size_t need_full = (size_t)WS_FLOATS_FULL * sizeof(float);
  if (ws_size < need_full) return;  // ws measured 256 MB (R2); guard only

  const ushort* GT = (const ushort*)(ws + OFF_GT);
  const ushort* GI = (const ushort*)(ws + OFF_GI);
  k_mean5      <<<256,  256, 0, stream>>>(fT, ws);
  k_prep5      <<<1024, 256, 0, stream>>>(fT, fI, ws);
  k_sweep_mfma5<<<512,  256, 0, stream>>>(GT, GI, ws, 0);  // colmax
  k_params5    <<<64,   256, 0, stream>>>(ws);
  k_sweep_mfma5<<<512,  256, 0, stream>>>(GT, GI, ws, 1);  // Wsum
  k_gamma5     <<<64,   256, 0, stream>>>(ws);
  k_sweep_mfma5<<<512,  256, 0, stream>>>(GI, GT, ws, 2);  // maxv
  k_final5     <<<1,    256, 0, stream>>>(ws, out);
}